// Round 1
// baseline (188.297 us; speedup 1.0000x reference)
//
#include <hip/hip_runtime.h>

#define BIGF 1e9f
#define JSTR 104      // cost row stride in floats (jo in [0,104); jo in [101,104) is always BIG pad)
#define BROWS 608     // buffer rows per batch: logical i in [-32, 576)
#define ROWOFF 32
#define TT 512
#define DD 256
#define NB 64

// ---------- DPP wave shifts: lane i <- lane i-1 (shr) / lane i+1 (shl); invalid lanes get `oldv`
__device__ __forceinline__ float dpp_wave_shr1(float x, float oldv) {
  int r = __builtin_amdgcn_update_dpp(__builtin_bit_cast(int, oldv),
                                      __builtin_bit_cast(int, x),
                                      0x138, 0xF, 0xF, false);  // WAVE_SHR1
  return __builtin_bit_cast(float, r);
}
__device__ __forceinline__ float dpp_wave_shl1(float x, float oldv) {
  int r = __builtin_amdgcn_update_dpp(__builtin_bit_cast(int, oldv),
                                      __builtin_bit_cast(int, x),
                                      0x130, 0xF, 0xF, false);  // WAVE_SHL1
  return __builtin_bit_cast(float, r);
}

// ---------- Kernel A: inverse row norms for x1 and x2 ----------
__global__ __launch_bounds__(256) void norm_kernel(const float* __restrict__ x1,
                                                   const float* __restrict__ x2,
                                                   float* __restrict__ rinv1,
                                                   float* __restrict__ rinv2) {
  const int w = threadIdx.x >> 6;
  const int lane = threadIdx.x & 63;
  const int row = blockIdx.x * 4 + w;  // 0 .. 65535
  const float* src;
  float* dst;
  if (row < NB * TT) {
    src = x1 + (size_t)row * DD;
    dst = rinv1 + row;
  } else {
    src = x2 + (size_t)(row - NB * TT) * DD;
    dst = rinv2 + (row - NB * TT);
  }
  const float4 v = *(const float4*)(src + lane * 4);
  float s = v.x * v.x + v.y * v.y + v.z * v.z + v.w * v.w;
#pragma unroll
  for (int off = 32; off > 0; off >>= 1) s += __shfl_down(s, off, 64);
  if (lane == 0) *dst = 1.0f / fmaxf(sqrtf(s), 1e-8f);
}

// ---------- Kernel F: BIG-fill border rows (logical i in [-32,0) and [512,544)) ----------
__global__ __launch_bounds__(256) void fill_kernel(float* __restrict__ costX) {
  const int idx = blockIdx.x * 256 + threadIdx.x;
  const int total = NB * 64 * JSTR;
  if (idx >= total) return;
  const int jo = idx % JSTR;
  const int rb = idx / JSTR;
  const int r = rb % 64;
  const int b = rb / 64;
  const int row = (r < 32) ? r : (544 + (r - 32));  // buffer rows [0,32) and [544,576)
  costX[((size_t)b * BROWS + row) * JSTR + jo] = BIGF;
}

// ---------- Kernel B: banded cost = 1 - dot * rinv1[i] * rinv2[j], stored [b][i+32][jo] ----------
__global__ __launch_bounds__(256) void cost_kernel(const float* __restrict__ x1,
                                                   const float* __restrict__ x2,
                                                   const float* __restrict__ rinv1,
                                                   const float* __restrict__ rinv2,
                                                   float* __restrict__ costX) {
  const int jt = blockIdx.x;  // 0..2
  const int it = blockIdx.y;  // 0..7
  const int b = blockIdx.z;   // 0..63
  const int i0 = it * 64;
  const int j0 = i0 - 50 + jt * 64;
  __shared__ __align__(16) float s1[32][68];  // K-major, stride 68 (272B, 16B-aligned rows)
  __shared__ __align__(16) float s2[32][68];
  const int t = threadIdx.x;
  const int tx = t & 15;
  const int ty = t >> 4;
  const int lr = t >> 3;  // 0..31
  const int lf = t & 7;   // float4 slot in 32-wide K chunk
  const float* x1b = x1 + (size_t)b * (TT * DD);
  const float* x2b = x2 + (size_t)b * (TT * DD);
  float acc[4][4];
#pragma unroll
  for (int r = 0; r < 4; ++r)
#pragma unroll
    for (int c = 0; c < 4; ++c) acc[r][c] = 0.f;

  for (int kc = 0; kc < DD; kc += 32) {
    __syncthreads();
#pragma unroll
    for (int h = 0; h < 2; ++h) {
      const int r = lr + h * 32;
      const int gi = i0 + r;  // always in [0,512)
      const float4 v1 = *(const float4*)(x1b + (size_t)gi * DD + kc + lf * 4);
      int gj = j0 + r;
      gj = gj < 0 ? 0 : (gj > TT - 1 ? TT - 1 : gj);
      const float4 v2 = *(const float4*)(x2b + (size_t)gj * DD + kc + lf * 4);
      s1[lf * 4 + 0][r] = v1.x; s1[lf * 4 + 1][r] = v1.y;
      s1[lf * 4 + 2][r] = v1.z; s1[lf * 4 + 3][r] = v1.w;
      s2[lf * 4 + 0][r] = v2.x; s2[lf * 4 + 1][r] = v2.y;
      s2[lf * 4 + 2][r] = v2.z; s2[lf * 4 + 3][r] = v2.w;
    }
    __syncthreads();
#pragma unroll
    for (int kk = 0; kk < 32; ++kk) {
      const float4 a = *(const float4*)&s1[kk][ty * 4];
      const float4 bb = *(const float4*)&s2[kk][tx * 4];
      acc[0][0] += a.x * bb.x; acc[0][1] += a.x * bb.y; acc[0][2] += a.x * bb.z; acc[0][3] += a.x * bb.w;
      acc[1][0] += a.y * bb.x; acc[1][1] += a.y * bb.y; acc[1][2] += a.y * bb.z; acc[1][3] += a.y * bb.w;
      acc[2][0] += a.z * bb.x; acc[2][1] += a.z * bb.y; acc[2][2] += a.z * bb.z; acc[2][3] += a.z * bb.w;
      acc[3][0] += a.w * bb.x; acc[3][1] += a.w * bb.y; acc[3][2] += a.w * bb.z; acc[3][3] += a.w * bb.w;
    }
  }
  float r1v[4], r2v[4];
#pragma unroll
  for (int r = 0; r < 4; ++r) r1v[r] = rinv1[b * TT + i0 + ty * 4 + r];
#pragma unroll
  for (int c = 0; c < 4; ++c) {
    int j = j0 + tx * 4 + c;
    int jc = j < 0 ? 0 : (j > TT - 1 ? TT - 1 : j);
    r2v[c] = rinv2[b * TT + jc];
  }
  float* cb = costX + (size_t)b * (BROWS * JSTR);
#pragma unroll
  for (int r = 0; r < 4; ++r) {
#pragma unroll
    for (int c = 0; c < 4; ++c) {
      const int i = i0 + ty * 4 + r;
      const int j = j0 + tx * 4 + c;
      const int jo = j - i + 50;
      if (jo >= 0 && jo < JSTR) {
        const bool valid = (j >= 0) && (j < TT) && (jo <= 100);
        const float val = valid ? (1.0f - acc[r][c] * r1v[r] * r2v[c]) : BIGF;
        cb[(size_t)(i + ROWOFF) * JSTR + jo] = val;
      }
    }
  }
}

// ---------- Kernel C: anti-diagonal DP, one wave per batch ----------
// k = i-j+50 in [0,100]; diagonal d = i+j, parity p = d&1, m = d>>1.
// Lane l holds cell k = 2l+p: i = m+l+p-25, j = m-l+25, jo = 100-2l-p.
// Recurrence: new[k] = c + min(prev1[k-1], prev1[k+1], prev2[k])
//   p=1: k-1 -> prev lane l (no shift), k+1 -> prev lane l+1 (wave_shl1)
//   p=0: k-1 -> prev lane l-1 (wave_shr1), k+1 -> prev lane l (no shift)
// All invalid cells read BIG from the pre-filled buffer (border rows + jo pad);
// lane 51's cost address always lands in the jo>=101 BIG pad -> firewall keeps
// lanes >=52 (whose addresses wrap into the previous row) from ever reaching lane <=50.
__global__ __launch_bounds__(64) void dtw_dp_kernel(const float* __restrict__ costX,
                                                    float* __restrict__ out) {
  const int b = blockIdx.x;
  const int l = threadIdx.x;
  const float* base = costX + (size_t)b * (BROWS * JSTR);
  // element offset for odd diags (d=1 start): (l+8)*104 + 99-2l = 102l+931
  // even diags (d=2 start): 102l+932; each +2 diagonals -> +JSTR
  const float* pO = base + (102 * l + 931);
  const float* pE = base + (102 * l + 932);
  float cr[32];
#pragma unroll
  for (int t2 = 0; t2 < 16; ++t2) {
    cr[2 * t2] = *pO; pO += JSTR;      // d = 2*t2+1
    cr[2 * t2 + 1] = *pE; pE += JSTR;  // d = 2*t2+2
  }
  float prev2 = BIGF;
  const float c00 = base[ROWOFF * JSTR + 50];  // cost(0,0)
  float prev1 = (l == 25) ? c00 : BIGF;        // diagonal d=0
  float ans = BIGF;
  for (int it = 0; it < 32; ++it) {
#pragma unroll
    for (int u = 0; u < 16; ++u) {
      // odd diagonal step (p=1)
      const float c1 = cr[2 * u];
      cr[2 * u] = *pO; pO += JSTR;  // prefetch d+32
      const float sh = dpp_wave_shl1(prev1, BIGF);
      const float m3 = fminf(fminf(prev1, sh), prev2);
      prev2 = prev1;
      prev1 = c1 + m3;
      // even diagonal step (p=0)
      const float c2 = cr[2 * u + 1];
      cr[2 * u + 1] = *pE; pE += JSTR;
      const float sh2 = dpp_wave_shr1(prev1, BIGF);
      const float m32 = fminf(fminf(sh2, prev1), prev2);
      prev2 = prev1;
      prev1 = c2 + m32;
      if (u == 14) {
        if (it == 31) ans = prev1;  // after d = 1022: cell (511,511) at lane 25
      }
    }
  }
  if (l == 25) out[b] = ans;
}

extern "C" void kernel_launch(void* const* d_in, const int* in_sizes, int n_in,
                              void* d_out, int out_size, void* d_ws, size_t ws_size,
                              hipStream_t stream) {
  const float* x1 = (const float*)d_in[0];
  const float* x2 = (const float*)d_in[1];
  float* out = (float*)d_out;
  float* costX = (float*)d_ws;                        // 64*608*104 floats = 16.2 MB
  float* rinv1 = costX + (size_t)NB * BROWS * JSTR;   // 64*512 floats
  float* rinv2 = rinv1 + NB * TT;                     // 64*512 floats

  norm_kernel<<<16384, 256, 0, stream>>>(x1, x2, rinv1, rinv2);
  fill_kernel<<<(NB * 64 * JSTR + 255) / 256, 256, 0, stream>>>(costX);
  dim3 g(3, 8, NB);
  cost_kernel<<<g, 256, 0, stream>>>(x1, x2, rinv1, rinv2, costX);
  dtw_dp_kernel<<<NB, 64, 0, stream>>>(costX, out);
}